// Round 1
// 289.650 us; speedup vs baseline: 1.0237x; 1.0237x over previous
//
#include <hip/hip_runtime.h>
#include <math.h>

#define BB 8
#define TT 4096
#define TP1 4097
#define HH 1024
#define NHD 16

__device__ __forceinline__ float dot4(const float4& a, const float4& b) {
  return a.x*b.x + a.y*b.y + a.z*b.z + a.w*b.w;
}

// ---------------- K1: qbuf[b][j] = 0.125*(cell[b,:]·Wq[j,:] + bq[j]) ----------------
// grid 256 (j-tiles of 4), block 256 = 4 jj-waves x 64 lanes
__global__ __launch_bounds__(256) void k_q(const float* __restrict__ cell,
                                           const float* __restrict__ Wq,
                                           const float* __restrict__ bq,
                                           float* __restrict__ qbuf) {
  __shared__ float cs[BB * HH];  // 32 KB
  int tid = threadIdx.x;
  #pragma unroll
  for (int m = 0; m < 8; m++) {
    int idx4 = tid + (m << 8);
    ((float4*)cs)[idx4] = ((const float4*)cell)[idx4];
  }
  __syncthreads();
  int jj = tid >> 6, lane = tid & 63;
  int j = blockIdx.x * 4 + jj;
  float acc[BB];
  #pragma unroll
  for (int b = 0; b < BB; b++) acc[b] = 0.f;
  #pragma unroll
  for (int k = 0; k < 4; k++) {
    int i = (k << 8) + (lane << 2);
    float4 w = *(const float4*)&Wq[(size_t)j * HH + i];
    #pragma unroll
    for (int b = 0; b < BB; b++) acc[b] += dot4(w, *(const float4*)&cs[b * HH + i]);
  }
  #pragma unroll
  for (int b = 0; b < BB; b++) {
    acc[b] += __shfl_xor(acc[b], 1);  acc[b] += __shfl_xor(acc[b], 2);
    acc[b] += __shfl_xor(acc[b], 4);  acc[b] += __shfl_xor(acc[b], 8);
    acc[b] += __shfl_xor(acc[b], 16); acc[b] += __shfl_xor(acc[b], 32);
  }
  if (lane == 0) {
    float bqv = bq[j];
    #pragma unroll
    for (int b = 0; b < BB; b++) qbuf[b * HH + j] = 0.125f * (acc[b] + bqv);
  }
}

// ---------------- K2: qWkT[b][i][h] = sum_d qbuf[b][h*64+d]*Wk[h*64+d][i] ----------------
// grid 256 = h(16) x ic(16); block 256 = 4 d-groups x 64 i-lanes. Also qbk[b][h].
__global__ __launch_bounds__(256) void k_qwk(const float* __restrict__ qbuf,
                                             const float* __restrict__ Wk,
                                             const float* __restrict__ bk,
                                             float* __restrict__ qWkT,
                                             float* __restrict__ qbk) {
  __shared__ float q_s[BB * 64];
  __shared__ float red[4 * 64 * 9];  // padded +1
  int tid = threadIdx.x;
  int h = blockIdx.x >> 4, ic = blockIdx.x & 15;
  if (tid < 128) {
    int b = tid >> 4, dq = tid & 15;
    ((float4*)q_s)[tid] = ((const float4*)qbuf)[(b << 8) + (h << 4) + dq];
  }
  __syncthreads();
  int dg = tid >> 6, lane = tid & 63;
  int i = (ic << 6) + lane;
  float acc[BB];
  #pragma unroll
  for (int b = 0; b < BB; b++) acc[b] = 0.f;
  #pragma unroll
  for (int dd = 0; dd < 16; dd++) {
    int d = (dg << 4) + dd;
    float wk = Wk[(size_t)((h << 6) + d) * HH + i];
    #pragma unroll
    for (int b = 0; b < BB; b++) acc[b] += q_s[(b << 6) + d] * wk;
  }
  #pragma unroll
  for (int b = 0; b < BB; b++) red[((dg << 6) + lane) * 9 + b] = acc[b];
  __syncthreads();
  #pragma unroll
  for (int r = 0; r < 2; r++) {
    int o = tid + (r << 8);           // 512 outputs = 64 i x 8 b
    int il = o >> 3, b = o & 7;
    float s = 0.f;
    #pragma unroll
    for (int g = 0; g < 4; g++) s += red[((g << 6) + il) * 9 + b];
    qWkT[((size_t)(b << 10) + (ic << 6) + il) * NHD + h] = s;
  }
  if (ic == 0 && tid < 8) {
    float s = 0.f;
    for (int d = 0; d < 64; d++) s += q_s[(tid << 6) + d] * bk[(h << 6) + d];
    qbk[tid * NHD + h] = s;
  }
}

// ---------------- K3: scores -> unnormalized exp, probsT[b][t][16] + Spart ----------------
// v2: grid 1024 = b(8) x tile(128 rows of 32); block 256 = 16 kq-groups x 16 row-groups.
// Each thread: 2 t-rows x 16 h accumulators, 1/16 of the i-dim (K-split 16).
// kv staged TRANSPOSED in LDS (kvT[i][row], stride 34 -> conflict-free b64 reads);
// q chunk (64 i x 16 h) staged in LDS (stride 20), read as broadcast b128 -> no
// per-FMA global loads. Double-buffered, ONE barrier per chunk, loads issued
// before compute / LDS-writes after (T14 issue-early/write-late).
__global__ __launch_bounds__(256, 4) void k_scores(const float* __restrict__ hid,
                                                   const float* __restrict__ qWkT,
                                                   const float* __restrict__ qbk,
                                                   const int* __restrict__ mask,
                                                   float* __restrict__ probsT,
                                                   float* __restrict__ Spart) {
  __shared__ float S[6912];     // KV0[2176] KV1[2176] QT0[1280] QT1[1280] = 27.6 KB
  __shared__ float qbk_s[NHD];
  int tid = threadIdx.x;
  int b = blockIdx.x >> 7, tile = blockIdx.x & 127;
  int t0 = tile << 5;
  if (tid < NHD) qbk_s[tid] = qbk[b * NHD + tid];
  int kq = tid >> 4, rg = tid & 15;     // compute coords
  int r = tid >> 4, c4 = tid & 15;      // staging coords (rows 0..15 / +16)
  const float* src = hid + ((size_t)(b * TP1) + t0) * HH;
  const float4* qsrc4 = (const float4*)qWkT;  // [b*4096 + cc*256 + tid]

  float* KV0 = S;
  float* KV1 = S + 2176;
  float* QT0 = S + 4352;
  float* QT1 = S + 5632;

  // prologue: stage chunk 0
  {
    float4 v0 = *(const float4*)&src[(size_t)r * HH + (c4 << 2)];
    float4 v1 = *(const float4*)&src[(size_t)(r + 16) * HH + (c4 << 2)];
    float4 vq = qsrc4[(b << 12) + tid];
    #pragma unroll
    for (int c = 0; c < 4; c++) {
      KV0[((c4 << 2) + c) * 34 + r]      = (&v0.x)[c];
      KV0[((c4 << 2) + c) * 34 + r + 16] = (&v1.x)[c];
    }
    *(float4*)&QT0[(tid >> 2) * 20 + ((tid & 3) << 2)] = vq;
  }
  __syncthreads();

  float acc0[16], acc1[16];
  #pragma unroll
  for (int h = 0; h < 16; h++) { acc0[h] = 0.f; acc1[h] = 0.f; }

  for (int cc = 0; cc < 16; cc++) {
    int cur = cc & 1;
    const float* kvb = cur ? KV1 : KV0;
    const float* qtb = cur ? QT1 : QT0;
    float* dkv = cur ? KV0 : KV1;
    float* dqt = cur ? QT0 : QT1;
    float4 v0, v1, vq;
    bool hasNext = (cc < 15);
    if (hasNext) {   // issue global loads EARLY; latency hides under the FMAs
      const float* s2 = src + ((cc + 1) << 6);
      v0 = *(const float4*)&s2[(size_t)r * HH + (c4 << 2)];
      v1 = *(const float4*)&s2[(size_t)(r + 16) * HH + (c4 << 2)];
      vq = qsrc4[(b << 12) + ((cc + 1) << 8) + tid];
    }
    #pragma unroll
    for (int ii = 0; ii < 4; ii++) {
      int il = (kq << 2) + ii;
      float2 kv2 = *(const float2*)&kvb[il * 34 + (rg << 1)];
      float qv[16];
      *(float4*)&qv[0]  = *(const float4*)&qtb[il * 20];
      *(float4*)&qv[4]  = *(const float4*)&qtb[il * 20 + 4];
      *(float4*)&qv[8]  = *(const float4*)&qtb[il * 20 + 8];
      *(float4*)&qv[12] = *(const float4*)&qtb[il * 20 + 12];
      #pragma unroll
      for (int h = 0; h < 16; h++) {
        acc0[h] += kv2.x * qv[h];
        acc1[h] += kv2.y * qv[h];
      }
    }
    if (hasNext) {   // write LATE (vmcnt drains here, after the compute)
      #pragma unroll
      for (int c = 0; c < 4; c++) {
        dkv[((c4 << 2) + c) * 34 + r]      = (&v0.x)[c];
        dkv[((c4 << 2) + c) * 34 + r + 16] = (&v1.x)[c];
      }
      *(float4*)&dqt[(tid >> 2) * 20 + ((tid & 3) << 2)] = vq;
    }
    __syncthreads();
  }

  // reduce over the 16 kq-groups: 4 intra-wave (xor 16,32), then 4 waves via LDS
  #pragma unroll
  for (int h = 0; h < 16; h++) {
    acc0[h] += __shfl_xor(acc0[h], 16); acc0[h] += __shfl_xor(acc0[h], 32);
    acc1[h] += __shfl_xor(acc1[h], 16); acc1[h] += __shfl_xor(acc1[h], 32);
  }
  int w = tid >> 6;
  if ((tid & 48) == 0) {               // lanes 0..15 of each wave
    float* rp = &S[((w << 4) + rg) * 36];   // red[4][16][36], reuses KV region
    *(float4*)&rp[0]  = make_float4(acc0[0],  acc0[1],  acc0[2],  acc0[3]);
    *(float4*)&rp[4]  = make_float4(acc0[4],  acc0[5],  acc0[6],  acc0[7]);
    *(float4*)&rp[8]  = make_float4(acc0[8],  acc0[9],  acc0[10], acc0[11]);
    *(float4*)&rp[12] = make_float4(acc0[12], acc0[13], acc0[14], acc0[15]);
    *(float4*)&rp[16] = make_float4(acc1[0],  acc1[1],  acc1[2],  acc1[3]);
    *(float4*)&rp[20] = make_float4(acc1[4],  acc1[5],  acc1[6],  acc1[7]);
    *(float4*)&rp[24] = make_float4(acc1[8],  acc1[9],  acc1[10], acc1[11]);
    *(float4*)&rp[28] = make_float4(acc1[12], acc1[13], acc1[14], acc1[15]);
  }
  __syncthreads();
  if (tid < 128) {
    int row = tid >> 2, hq = tid & 3;
    float4 sv = make_float4(0.f, 0.f, 0.f, 0.f);
    #pragma unroll
    for (int ww = 0; ww < 4; ww++) {
      const float* rp = &S[((ww << 4) + (row >> 1)) * 36 + ((row & 1) << 4) + (hq << 2)];
      float4 rv = *(const float4*)rp;
      sv.x += rv.x; sv.y += rv.y; sv.z += rv.z; sv.w += rv.w;
    }
    int mk = mask[b * TT + t0 + row];
    float4 e;
    e.x = mk ? __expf(sv.x + qbk_s[(hq << 2) + 0]) : 0.f;
    e.y = mk ? __expf(sv.y + qbk_s[(hq << 2) + 1]) : 0.f;
    e.z = mk ? __expf(sv.z + qbk_s[(hq << 2) + 2]) : 0.f;
    e.w = mk ? __expf(sv.w + qbk_s[(hq << 2) + 3]) : 0.f;
    *(float4*)&probsT[((size_t)(b * TT + t0 + row)) * NHD + (hq << 2)] = e;
    *(float4*)&S[4352 + (row << 4) + (hq << 2)] = e;   // e_sh (reuses QT0)
  }
  __syncthreads();
  if (tid < 64) {
    int g = tid >> 4, h2 = tid & 15;
    float s2 = 0.f;
    #pragma unroll
    for (int j = 0; j < 8; j++) s2 += S[4352 + ((g + (j << 2)) << 4) + h2];
    s2 += __shfl_xor(s2, 16);
    s2 += __shfl_xor(s2, 32);
    if (tid < 16) Spart[((size_t)(b << 7) + tile) * NHD + h2] = s2;
  }
}

// ---------------- K4: Sinv[b][h] = 1 / sum_tiles Spart (128 tiles now) ----------------
__global__ void k_sinv(const float* __restrict__ Spart, float* __restrict__ Sinv) {
  int tid = threadIdx.x;  // 128
  float s = 0.f;
  for (int c = 0; c < 128; c++) s += Spart[(size_t)((tid >> 4) * 128 + c) * NHD + (tid & 15)];
  Sinv[tid] = 1.f / s;
}

// ---------------- K5: ctxin[b][h][i] += sum_t e[t][h]*kv[t][i] (unnormalized) ----------------
// v2: probsT rows staged once into LDS (16 KB), read via pure-broadcast b128;
// kv loads batched 8-deep (8 KB/wave in flight) before each FMA block.
__global__ __launch_bounds__(256) void k_ctx(const float* __restrict__ hid,
                                             const float* __restrict__ probsT,
                                             float* __restrict__ ctxin) {
  __shared__ float p_s[256 * 16];     // 16 KB: [w*64 + k][16]
  __shared__ float red2[2][64 * 64];  // 32 KB
  int tid = threadIdx.x;
  int b = blockIdx.x >> 6, ic = (blockIdx.x >> 4) & 3, th = blockIdx.x & 15;
  int w = __builtin_amdgcn_readfirstlane(tid >> 6);
  int lane = tid & 63;
  // stage this block's 256 probsT rows: row(w',k) = th*4 + w' + 64k
  #pragma unroll
  for (int m = 0; m < 4; m++) {
    int idx = tid + (m << 8);
    int rr = idx >> 2, qq = idx & 3;
    int wp = rr >> 6, k = rr & 63;
    ((float4*)p_s)[idx] =
        *(const float4*)&probsT[((size_t)(b << 12) + (th << 2) + wp + (k << 6)) * NHD + (qq << 2)];
  }
  __syncthreads();
  int t0 = (th << 2) + w;
  const float* kvp = hid + (size_t)b * TP1 * HH + (ic << 8) + (lane << 2);
  float4 acc4[NHD];
  #pragma unroll
  for (int h = 0; h < NHD; h++) acc4[h] = make_float4(0.f, 0.f, 0.f, 0.f);
  for (int it8 = 0; it8 < 64; it8 += 8) {
    float4 kv[8];
    #pragma unroll
    for (int m = 0; m < 8; m++)
      kv[m] = *(const float4*)&kvp[(size_t)(t0 + ((it8 + m) << 6)) * HH];
    #pragma unroll
    for (int m = 0; m < 8; m++) {
      const float* pp = &p_s[((w << 6) + it8 + m) << 4];
      float pv[16];
      *(float4*)&pv[0]  = *(const float4*)&pp[0];
      *(float4*)&pv[4]  = *(const float4*)&pp[4];
      *(float4*)&pv[8]  = *(const float4*)&pp[8];
      *(float4*)&pv[12] = *(const float4*)&pp[12];
      #pragma unroll
      for (int h = 0; h < NHD; h++) {
        acc4[h].x += kv[m].x * pv[h]; acc4[h].y += kv[m].y * pv[h];
        acc4[h].z += kv[m].z * pv[h]; acc4[h].w += kv[m].w * pv[h];
      }
    }
  }
  if (w < 2) {
    #pragma unroll
    for (int h = 0; h < NHD; h++)
      *(float4*)&red2[w][(lane << 6) + (h << 2)] = acc4[h];
  }
  __syncthreads();
  if (w >= 2) {
    #pragma unroll
    for (int h = 0; h < NHD; h++) {
      float4 r = *(const float4*)&red2[w - 2][(lane << 6) + (h << 2)];
      r.x += acc4[h].x; r.y += acc4[h].y; r.z += acc4[h].z; r.w += acc4[h].w;
      *(float4*)&red2[w - 2][(lane << 6) + (h << 2)] = r;
    }
  }
  __syncthreads();
  #pragma unroll
  for (int j = 0; j < 4; j++) {
    int k = tid + (j << 8);  // 1024 float4 = 64 i-quads x 16 h
    float4 a = ((const float4*)red2[0])[k];
    float4 c2 = ((const float4*)red2[1])[k];
    int li = k >> 4, h = k & 15;
    float* dst = ctxin + (((size_t)(b << 4) + h) << 10) + (ic << 8) + (li << 2);
    atomicAdd(dst + 0, a.x + c2.x);
    atomicAdd(dst + 1, a.y + c2.y);
    atomicAdd(dst + 2, a.z + c2.z);
    atomicAdd(dst + 3, a.w + c2.w);
  }
}

// ---------------- K6: out[b][h*64+(j%64)] = Sinv[b][h]*(Wv[j,:]·ctxin[b][h][:]) + bv[j] ----------------
// grid 256 (j-tiles of 4, within one head); block 256 = 4 jj-waves x 64 lanes
__global__ __launch_bounds__(256) void k_out(const float* __restrict__ Wv,
                                             const float* __restrict__ bv,
                                             const float* __restrict__ ctxin,
                                             const float* __restrict__ Sinv,
                                             float* __restrict__ out) {
  __shared__ float cs[BB * HH];  // 32 KB
  int tid = threadIdx.x;
  int h = blockIdx.x >> 4;
  int j0 = blockIdx.x * 4;
  #pragma unroll
  for (int m = 0; m < 8; m++) {
    int idx4 = tid + (m << 8);
    int b = idx4 >> 8, i4 = idx4 & 255;
    ((float4*)cs)[idx4] = ((const float4*)ctxin)[(((b << 4) + h) << 8) + i4];
  }
  __syncthreads();
  int jj = tid >> 6, lane = tid & 63;
  int j = j0 + jj;
  float acc[BB];
  #pragma unroll
  for (int b = 0; b < BB; b++) acc[b] = 0.f;
  #pragma unroll
  for (int k = 0; k < 4; k++) {
    int i = (k << 8) + (lane << 2);
    float4 w = *(const float4*)&Wv[(size_t)j * HH + i];
    #pragma unroll
    for (int b = 0; b < BB; b++) acc[b] += dot4(w, *(const float4*)&cs[b * HH + i]);
  }
  #pragma unroll
  for (int b = 0; b < BB; b++) {
    acc[b] += __shfl_xor(acc[b], 1);  acc[b] += __shfl_xor(acc[b], 2);
    acc[b] += __shfl_xor(acc[b], 4);  acc[b] += __shfl_xor(acc[b], 8);
    acc[b] += __shfl_xor(acc[b], 16); acc[b] += __shfl_xor(acc[b], 32);
  }
  if (lane == 0) {
    float bvj = bv[j];
    #pragma unroll
    for (int b = 0; b < BB; b++)
      out[b * HH + j] = Sinv[b * NHD + h] * acc[b] + bvj;
  }
}

extern "C" void kernel_launch(void* const* d_in, const int* in_sizes, int n_in,
                              void* d_out, int out_size, void* d_ws, size_t ws_size,
                              hipStream_t stream) {
  const float* hid  = (const float*)d_in[0];  // (8, 4097, 1024)
  const float* cell = (const float*)d_in[1];  // (8, 1024)
  const float* Wq   = (const float*)d_in[2];
  const float* bq   = (const float*)d_in[3];
  const float* Wk   = (const float*)d_in[4];
  const float* bk   = (const float*)d_in[5];
  const float* Wv   = (const float*)d_in[6];
  const float* bv   = (const float*)d_in[7];
  const int*  mask  = (const int*)d_in[8];    // (8, 4096)
  float* out = (float*)d_out;                 // (8, 1024)

  float* ws = (float*)d_ws;
  float* qbuf    = ws;             // 8192
  float* qWkT    = ws + 8192;      // 131072  [b][i][16]
  float* qbk     = ws + 139264;    // 128
  float* probsT  = ws + 139392;    // 524288  [b][t][16] unnormalized exp
  float* Spart   = ws + 663680;    // 16384   (128 tiles x 16 h x 8 b)
  float* Sinv    = ws + 680064;    // 128
  float* ctxin   = ws + 680192;    // 131072  [b][h][1024] (atomic accum)

  hipMemsetAsync(ctxin, 0, (size_t)BB * NHD * HH * sizeof(float), stream);
  hipLaunchKernelGGL(k_q,      dim3(256),  dim3(256), 0, stream, cell, Wq, bq, qbuf);
  hipLaunchKernelGGL(k_qwk,    dim3(256),  dim3(256), 0, stream, qbuf, Wk, bk, qWkT, qbk);
  hipLaunchKernelGGL(k_scores, dim3(1024), dim3(256), 0, stream, hid, qWkT, qbk, mask, probsT, Spart);
  hipLaunchKernelGGL(k_sinv,   dim3(1),    dim3(128), 0, stream, Spart, Sinv);
  hipLaunchKernelGGL(k_ctx,    dim3(512),  dim3(256), 0, stream, hid, probsT, ctxin);
  hipLaunchKernelGGL(k_out,    dim3(256),  dim3(256), 0, stream, Wv, bv, ctxin, Sinv, out);
}